// Round 9
// baseline (410.519 us; speedup 1.0000x reference)
//
#include <hip/hip_runtime.h>

typedef __bf16 bf16_t;
typedef bf16_t bf16x8 __attribute__((ext_vector_type(8)));
typedef float f32x4 __attribute__((ext_vector_type(4)));

#define HIDDEN 2048
#define SEQ 2048
#define BATCH 2
#define NHEADS 16
#define HDIM 128
#define MTOT (BATCH*SEQ)
#define SCALE 0.088388347648318447f
#define C1EXP2 0.12753102158508967f   /* SCALE * log2(e) */
#define LOG2E  1.4426950408889634f

// device exp2 without touching libm names (math.h macro collision on this toolchain)
__device__ __forceinline__ float dev_exp2(float x) { return __builtin_amdgcn_exp2f(x); }

// ---- async global->LDS (wave-uniform LDS base + lane*16, per m97) ----
typedef __attribute__((address_space(1))) const void gvoid_t;
typedef __attribute__((address_space(3))) void svoid_t;
__device__ __forceinline__ void async_copy16(const bf16_t* g, bf16_t* l) {
  __builtin_amdgcn_global_load_lds((gvoid_t*)g, (svoid_t*)l, 16, 0, 0);
}

// ---- fused fp32 -> bf16 cast for x + 4 weights (one dispatch) ----
__global__ void cvt_all(const float* __restrict__ x,  const float* __restrict__ wq,
                        const float* __restrict__ wk, const float* __restrict__ wv,
                        const float* __restrict__ wo,
                        bf16_t* __restrict__ xb, bf16_t* __restrict__ wqkb,
                        bf16_t* __restrict__ wvb, bf16_t* __restrict__ wob) {
  const size_t HH = (size_t)HIDDEN * HIDDEN;
  const float* src; bf16_t* dst;
  switch (blockIdx.y) {
    case 0:  src = x;        dst = xb;        break;
    case 1:  src = x + HH;   dst = xb + HH;   break;
    case 2:  src = wq;       dst = wqkb;      break;
    case 3:  src = wk;       dst = wqkb + HH; break;
    case 4:  src = wv;       dst = wvb;       break;
    default: src = wo;       dst = wob;       break;
  }
  int i = blockIdx.x * 256 + threadIdx.x;     // HH/4 float4s per region
  float4 v = reinterpret_cast<const float4*>(src)[i];
  union { bf16_t h[4]; uint2 u; } t;
  t.h[0] = (bf16_t)v.x; t.h[1] = (bf16_t)v.y; t.h[2] = (bf16_t)v.z; t.h[3] = (bf16_t)v.w;
  reinterpret_cast<uint2*>(dst)[i] = t.u;
}

__global__ void pack_bias2(const float* __restrict__ a, const float* __restrict__ b2,
                           float* __restrict__ out) {
  int i = blockIdx.x * 256 + threadIdx.x;      // 0..4095
  out[i] = (i < HIDDEN) ? a[i] : b2[i - HIDDEN];
}

#define PHASE_SYNC do { __builtin_amdgcn_s_barrier();                          \
  asm volatile("s_waitcnt lgkmcnt(0)" ::: "memory");                           \
  __builtin_amdgcn_sched_barrier(0); } while (0)

// ---- gemm32: 256x128 tile, BK=32, 2 blocks/CU, depth-2 counted pipeline ----
// 8 waves 4M x 2N, per-wave 64x64 (acc 64 VGPR; launch_bounds(512,4) caps
// VGPR at 128 -> 4 waves/SIMD = 2 co-resident blocks -> cross-block overlap
// hides barrier/lgkm stalls (m114 mechanism, absent in the 1-block/CU 8-phase).
// LDS 3buf x (A 256x32 + B 128x32) x 2B = 72 KB.
// Per K-tile: 2 phases x 8 MFMA; ds_reads {af4+bf2, bf2} = per-wave minimum.
// Staging: 3 calls/wave/tile (A-lo, A-hi, B; 16 rows x 32 cols each), burst
// at P0 for tile t+2 into buf (t+2)%3 (last read tile t-1, >=2 barriers ago).
// Checkpoint at P1: vmcnt(3) retires exactly tile t+1 (issued (t-1)P0,
// 4 phases of cover); tail vmcnt(0). Swizzle: LDS[r][c] holds global chunk
// c ^ ((r>>1)&3); read chunk = quad ^ ((lr>>1)&3); source pre-swizzled
// chunk = (l&3) ^ ((l>>3)&3). All per-lane keys uniform in the frag base.
template<bool OUT_BF16, bool ROW_BIAS>
__global__ __launch_bounds__(512, 4)
void gemm32(const bf16_t* __restrict__ A, const bf16_t* __restrict__ Bt,
            const float* __restrict__ bias, void* __restrict__ Yv,
            int K, int ldY, int nbt) {
  __shared__ __align__(16) bf16_t As[3][256 * 32];   // 48 KB
  __shared__ __align__(16) bf16_t Bs[3][128 * 32];   // 24 KB
  const int tid  = threadIdx.x;
  const int lane = tid & 63;
  const int wv   = tid >> 6;                 // 0..7
  const int wr   = wv >> 1, wc = wv & 1;     // 4M x 2N wave grid
  const int lr   = lane & 15, quad = lane >> 4;
  const int kx   = (lr >> 1) & 3;            // read-side swizzle key

  const int wg  = blockIdx.x;
  const int cpx = gridDim.x >> 3;            // bijective XCD swizzle (grid%8==0)
  const int swz = (wg & 7) * cpx + (wg >> 3);
  const int m0  = (swz / nbt) * 256;
  const int n0  = (swz % nbt) * 128;

  f32x4 acc[4][4] = {};

  // staging: one call = 16 rows x 32 cols; lane l -> row l>>2, chunk l&3
  const int srow = lane >> 2;
  const int sch  = (lane & 3) ^ ((lane >> 3) & 3);
  const bf16_t* pA0 = A  + (size_t)(m0 +       wv * 16 + srow) * K + sch * 8;
  const bf16_t* pA1 = A  + (size_t)(m0 + 128 + wv * 16 + srow) * K + sch * 8;
  const bf16_t* pB  = Bt + (size_t)(n0 +       wv * 16 + srow) * K + sch * 8;
  const int lA0 = (wv * 16) * 32, lA1 = (128 + wv * 16) * 32, lB = (wv * 16) * 32;
  const int nt = K >> 5;

  // prologue: stage t0 (3 calls) + t1 (3 calls); vmcnt(3) -> t0 landed
  async_copy16(pA0,      &As[0][lA0]);
  async_copy16(pA1,      &As[0][lA1]);
  async_copy16(pB,       &Bs[0][lB]);
  async_copy16(pA0 + 32, &As[1][lA0]);
  async_copy16(pA1 + 32, &As[1][lA1]);
  async_copy16(pB  + 32, &Bs[1][lB]);
  asm volatile("s_waitcnt vmcnt(3)" ::: "memory");
  __builtin_amdgcn_s_barrier();

  bf16x8 af[4], bfr[2];
  for (int t = 0; t < nt; ++t) {
    const int buf = t % 3;

    // P0: read af[0..3] + bf(ni=0,1); stage tile t+2 (3 calls)
#pragma unroll
    for (int mi = 0; mi < 4; ++mi)
      af[mi] = *(const bf16x8*)&As[buf][(wr * 64 + mi * 16 + lr) * 32 + ((quad ^ kx) * 8)];
#pragma unroll
    for (int ni = 0; ni < 2; ++ni)
      bfr[ni] = *(const bf16x8*)&Bs[buf][(wc * 64 + ni * 16 + lr) * 32 + ((quad ^ kx) * 8)];
    if (t + 2 < nt) {
      const int b2 = (buf < 1) ? buf + 2 : buf - 1;   // (t+2) % 3
      const int ko = (t + 2) * 32;
      async_copy16(pA0 + ko, &As[b2][lA0]);
      async_copy16(pA1 + ko, &As[b2][lA1]);
      async_copy16(pB  + ko, &Bs[b2][lB]);
    }
    PHASE_SYNC;
    __builtin_amdgcn_s_setprio(1);
#pragma unroll
    for (int mi = 0; mi < 4; ++mi)
#pragma unroll
      for (int ni = 0; ni < 2; ++ni)
        acc[mi][ni] = __builtin_amdgcn_mfma_f32_16x16x32_bf16(af[mi], bfr[ni], acc[mi][ni], 0, 0, 0);
    __builtin_amdgcn_s_setprio(0);
    __builtin_amdgcn_s_barrier();

    // P1: read bf(ni=2,3); counted checkpoint; compute right half
#pragma unroll
    for (int ni = 0; ni < 2; ++ni)
      bfr[ni] = *(const bf16x8*)&Bs[buf][(wc * 64 + (2 + ni) * 16 + lr) * 32 + ((quad ^ kx) * 8)];
    if (t + 2 < nt) { asm volatile("s_waitcnt vmcnt(3)" ::: "memory"); }
    else            { asm volatile("s_waitcnt vmcnt(0)" ::: "memory"); }
    PHASE_SYNC;
    __builtin_amdgcn_s_setprio(1);
#pragma unroll
    for (int mi = 0; mi < 4; ++mi)
#pragma unroll
      for (int ni = 0; ni < 2; ++ni)
        acc[mi][2 + ni] = __builtin_amdgcn_mfma_f32_16x16x32_bf16(af[mi], bfr[ni], acc[mi][2 + ni], 0, 0, 0);
    __builtin_amdgcn_s_setprio(0);
    __builtin_amdgcn_s_barrier();
  }

  // epilogue
  float bc[4];
  if (!ROW_BIAS) {
#pragma unroll
    for (int fn = 0; fn < 4; ++fn) bc[fn] = bias[n0 + wc * 64 + fn * 16 + lr];
  }
#pragma unroll
  for (int fm = 0; fm < 4; ++fm) {
    const int rowb = m0 + wr * 64 + fm * 16 + quad * 4;
#pragma unroll
    for (int r = 0; r < 4; ++r) {
      const int row = rowb + r;
      const float brow = ROW_BIAS ? bias[row] : 0.0f;
      const size_t base = (size_t)row * ldY;
#pragma unroll
      for (int fn = 0; fn < 4; ++fn) {
        const int col = n0 + wc * 64 + fn * 16 + lr;
        float y = acc[fm][fn][r] + (ROW_BIAS ? brow : bc[fn]);
        if (OUT_BF16) ((bf16_t*)Yv)[base + col] = (bf16_t)y;
        else          ((float*)Yv)[base + col]  = y;
      }
    }
  }
}

// ---- gemm_tall: 256x128 tile, BK=64, 3-deep LDS pipeline (unchanged R5) ----
#define TSTG(ptr, t64, ldsbase) do {                                           \
  async_copy16((ptr) + (t64), (ldsbase));                                      \
  async_copy16((ptr) + (size_t)8 * K + (t64), (ldsbase) + 8 * 64);             \
} while (0)
#define TRD(kk) do {                                                           \
  _Pragma("unroll") for (int fi_ = 0; fi_ < 4; ++fi_)                          \
    af[fi_] = *(const bf16x8*)&As[buf][(wr * 64 + fi_ * 16 + lr) * 64          \
                  + ((((kk) * 4 + quad) ^ (lr & 7)) * 8)];                     \
  _Pragma("unroll") for (int fi_ = 0; fi_ < 4; ++fi_)                          \
    bf[fi_] = *(const bf16x8*)&Bs[buf][(wc * 64 + fi_ * 16 + lr) * 64          \
                  + ((((kk) * 4 + quad) ^ (lr & 7)) * 8)];                     \
} while (0)
#define TMM() do {                                                             \
  __builtin_amdgcn_s_setprio(1);                                               \
  _Pragma("unroll") for (int fm_ = 0; fm_ < 4; ++fm_)                          \
    _Pragma("unroll") for (int fn_ = 0; fn_ < 4; ++fn_)                        \
      acc[fm_][fn_] = __builtin_amdgcn_mfma_f32_16x16x32_bf16(                 \
          af[fm_], bf[fn_], acc[fm_][fn_], 0, 0, 0);                           \
  __builtin_amdgcn_s_setprio(0);                                               \
} while (0)

template<bool OUT_BF16, bool ROW_BIAS>
__global__ __launch_bounds__(512)
void gemm_tall(const bf16_t* __restrict__ A, const bf16_t* __restrict__ Bt,
               const float* __restrict__ bias, void* __restrict__ Yv,
               int K, int ldY, int nbt) {
  __shared__ __align__(16) bf16_t As[3][256 * 64];   // 96 KB
  __shared__ __align__(16) bf16_t Bs[3][128 * 64];   // 48 KB
  const int tid  = threadIdx.x;
  const int lane = tid & 63;
  const int wv   = tid >> 6;                 // 0..7
  const int wr   = wv >> 1, wc = wv & 1;     // 4M x 2N wave grid
  const int lr   = lane & 15, quad = lane >> 4;

  // bijective XCD swizzle (gridDim.x == 256 at both call sites)
  const int wg  = blockIdx.x;
  const int swz = (wg & 7) * 32 + (wg >> 3);
  const int m0  = (swz / nbt) * 256;
  const int n0  = (swz % nbt) * 128;

  f32x4 acc[4][4] = {};

  const int sub = lane >> 3, chv = (lane & 7) ^ sub;
  const int rih = wv * 16 + sub;
  const bf16_t* pA = A  + (size_t)(m0 + rih) * K + chv * 8;   // A0 unit; A1 = +128*K
  const bf16_t* pB = Bt + (size_t)(n0 + rih) * K + chv * 8;
  const size_t a1off = (size_t)128 * K;
  const int lwo = wv * 16 * 64;
  const int nt  = K >> 6;

  // prologue: t0 (6 calls) then t1 (6 calls); vmcnt(6) -> t0 landed
  TSTG(pA,         (size_t)0,  &As[0][lwo]);
  TSTG(pA + a1off, (size_t)0,  &As[0][128 * 64 + lwo]);
  TSTG(pB,         (size_t)0,  &Bs[0][lwo]);
  TSTG(pA,         (size_t)64, &As[1][lwo]);
  TSTG(pA + a1off, (size_t)64, &As[1][128 * 64 + lwo]);
  TSTG(pB,         (size_t)64, &Bs[1][lwo]);
  asm volatile("s_waitcnt vmcnt(6)" ::: "memory");
  __builtin_amdgcn_s_barrier();

  bf16x8 af[4], bf[4];
  for (int t = 0; t < nt; ++t) {
    const int buf = t % 3;

    // P0 (kk=0): reads + stage all 3 units of t+2 -> buf (t+2)%3
    TRD(0);
    if (t + 2 < nt) {
      const int b2 = (buf < 1) ? buf + 2 : buf - 1;   // (t+2)%3
      const size_t tk2 = (size_t)(t + 2) * 64;
      TSTG(pA,         tk2, &As[b2][lwo]);
      TSTG(pA + a1off, tk2, &As[b2][128 * 64 + lwo]);
      TSTG(pB,         tk2, &Bs[b2][lwo]);
    }
    PHASE_SYNC; TMM(); __builtin_amdgcn_s_barrier();

    // P1 (kk=1): reads + counted checkpoint
    TRD(1);
    if (t + 2 < nt) { asm volatile("s_waitcnt vmcnt(6)" ::: "memory"); }
    else            { asm volatile("s_waitcnt vmcnt(0)" ::: "memory"); }
    PHASE_SYNC; TMM(); __builtin_amdgcn_s_barrier();
  }

  // epilogue
  float bc[4];
  if (!ROW_BIAS) {
#pragma unroll
    for (int fn = 0; fn < 4; ++fn) bc[fn] = bias[n0 + wc * 64 + fn * 16 + lr];
  }
#pragma unroll
  for (int fm = 0; fm < 4; ++fm) {
    const int rowb = m0 + wr * 64 + fm * 16 + quad * 4;
#pragma unroll
    for (int r = 0; r < 4; ++r) {
      const int row = rowb + r;
      const float brow = ROW_BIAS ? bias[row] : 0.0f;
      const size_t base = (size_t)row * ldY;
#pragma unroll
      for (int fn = 0; fn < 4; ++fn) {
        const int col = n0 + wc * 64 + fn * 16 + lr;
        float y = acc[fm][fn][r] + (ROW_BIAS ? brow : bc[fn]);
        if (OUT_BF16) ((bf16_t*)Yv)[base + col] = (bf16_t)y;
        else          ((float*)Yv)[base + col]  = y;
      }
    }
  }
}

// ---- Flash attention v8 + T5 setprio (m191: +4-7% on attn) ----
#define BQ 256
#define BKV 64
#define LDQK 4096

__global__ __launch_bounds__(512)
void attn_kernel(const bf16_t* __restrict__ QK, const bf16_t* __restrict__ Vt,
                 const float* __restrict__ mask, bf16_t* __restrict__ O) {
  __shared__ __align__(16) bf16_t Ks[2][BKV * 128];  // 2 x 16 KB, swizzle key row&15
  __shared__ __align__(16) bf16_t Vs[2][HDIM * BKV]; // 2 x 16 KB, swizzle key d&7
  __shared__ __align__(16) bf16_t Ps[BQ * BKV];      // 32 KB, swizzle key row&7
  __shared__ __align__(16) float  Msk[SEQ];          // 8 KB, pre-scaled by log2e

  const int tid  = threadIdx.x;
  const int lane = tid & 63;
  const int wv   = tid >> 6;                       // 0..7; wave owns q rows [wv*32, wv*32+32)
  const int lr   = lane & 15, quad = lane >> 4;
  const int q0   = blockIdx.x * BQ;
  const int bh   = blockIdx.y;
  const int b    = bh >> 4, h = bh & 15;

  const bf16_t* Qg = QK + (size_t)(b * SEQ + q0) * LDQK + h * HDIM;
  const bf16_t* Kg = QK + (size_t)(b * SEQ) * LDQK + HIDDEN + h * HDIM;
  const bf16_t* Vg = Vt + (size_t)(h * HDIM) * MTOT + b * SEQ;
  const float*  mb = mask + b * SEQ;

  // Q fragments straight from global (one-time; L2/L3-served). 32 VGPRs.
  bf16x8 qf[2][4];
#pragma unroll
  for (int mi = 0; mi < 2; ++mi)
#pragma unroll
    for (int dk = 0; dk < 4; ++dk)
      qf[mi][dk] = *(const bf16x8*)(Qg + (size_t)(wv * 32 + mi * 16 + lr) * LDQK + dk * 32 + quad * 8);

  // mask -> LDS once, pre-scaled
  for (int i = tid; i < SEQ / 4; i += 512) {
    float4 mv = reinterpret_cast<const float4*>(mb)[i];
    Msk[i * 4 + 0] = mv.x * LOG2E;
    Msk[i * 4 + 1] = mv.y * LOG2E;
    Msk[i * 4 + 2] = mv.z * LOG2E;
    Msk[i * 4 + 3] = mv.w * LOG2E;
  }

  // staging: K tile 64x128 = 16 calls (2/wave); V tile 128x64 = 16 calls (2/wave)
  const int kcs = lane & 15;                       // K chunk (16B units)
  const int vcs = lane & 7;                        // V chunk
  const bf16_t* kgp[2]; const bf16_t* vgp[2];
  int lKo[2], lVo[2];
#pragma unroll
  for (int i = 0; i < 2; ++i) {
    int kr = wv * 8 + i * 4 + (lane >> 4);         // 0..63
    kgp[i] = Kg + (size_t)kr * LDQK + ((kcs ^ (kr & 15)) * 8);
    lKo[i] = (wv * 8 + i * 4) * 128;               // wave-uniform; HW adds lane*16B
    int vr = wv * 16 + i * 8 + (lane >> 3);        // 0..127
    vgp[i] = Vg + (size_t)vr * MTOT + ((vcs ^ (vr & 7)) * 8);
    lVo[i] = (wv * 16 + i * 8) * 64;
  }

  // drain Q/mask VMEM so in-loop vmcnt counts only staging ops
  asm volatile("s_waitcnt vmcnt(0)" ::: "memory");
#pragma unroll
  for (int i = 0; i < 2; ++i) async_copy16(kgp[i], &Ks[0][lKo[i]]);   // K(0)
#pragma unroll
  for (int i = 0; i < 2; ++i) async_copy16(vgp[i], &Vs[0][lVo[i]]);   // V(0)
  asm volatile("s_waitcnt lgkmcnt(0)" ::: "memory");                  // Msk writes done
  __builtin_amdgcn_s_barrier();                                       // Msk visible

  float l_st[2][4] = {};
  f32x4 oacc[2][8] = {};

  for (int kt = 0; kt < SEQ; kt += BKV) {
    const int cur = (kt >> 6) & 1;
    const bf16_t* Kc = &Ks[cur][0];
    const bf16_t* Vc = &Vs[cur][0];

    // WAR fence: all waves done reading Ks/Vs[cur^1] (iter t-1) and Ps
    asm volatile("s_waitcnt lgkmcnt(0)" ::: "memory");
    __builtin_amdgcn_s_barrier();
    if (kt + BKV < SEQ) {
#pragma unroll
      for (int i = 0; i < 2; ++i)
        async_copy16(kgp[i] + (size_t)(kt + BKV) * LDQK, &Ks[cur ^ 1][lKo[i]]);
#pragma unroll
      for (int i = 0; i < 2; ++i)
        async_copy16(vgp[i] + (kt + BKV), &Vs[cur ^ 1][lVo[i]]);
      asm volatile("s_waitcnt vmcnt(4)" ::: "memory");  // K(kt),V(kt) landed; next tile in flight
    } else {
      asm volatile("s_waitcnt vmcnt(0)" ::: "memory");
    }
    __builtin_amdgcn_s_barrier();   // K(kt),V(kt) visible to all waves
    __builtin_amdgcn_sched_barrier(0);

    float mk[4];
#pragma unroll
    for (int ni = 0; ni < 4; ++ni) mk[ni] = Msk[kt + ni * 16 + lr];

    // S = Q K^T  (per wave: [32 q][64 k])
    f32x4 sacc[2][4] = {};
#pragma unroll
    for (int dk = 0; dk < 4; ++dk) {
      bf16x8 kf[4];
#pragma unroll
      for (int ni = 0; ni < 4; ++ni)
        kf[ni] = *(const bf16x8*)&Kc[(ni * 16 + lr) * 128 + (((dk * 4 + quad) ^ lr) * 8)];
      __builtin_amdgcn_s_setprio(1);
#pragma unroll
      for (int mi = 0; mi < 2; ++mi)
#pragma unroll
        for (int ni = 0; ni < 4; ++ni)
          sacc[mi][ni] = __builtin_amdgcn_mfma_f32_16x16x32_bf16(qf[mi][dk], kf[ni], sacc[mi][ni], 0, 0, 0);
      __builtin_amdgcn_s_setprio(0);
    }

    // unnormalized P = exp2(S*C1 + mask*log2e); C-layout row = quad*4+r, col = lr
#pragma unroll
    for (int mi = 0; mi < 2; ++mi) {
#pragma unroll
      for (int r = 0; r < 4; ++r) {
        float p0 = dev_exp2(fmaf(sacc[mi][0][r], C1EXP2, mk[0]));
        float p1 = dev_exp2(fmaf(sacc[mi][1][r], C1EXP2, mk[1]));
        float p2 = dev_exp2(fmaf(sacc[mi][2][r], C1EXP2, mk[2]));
        float p3 = dev_exp2(fmaf(sacc[mi][3][r], C1EXP2, mk[3]));
        int pr = wv * 32 + mi * 16 + quad * 4 + r;
        int key = pr & 7;
        Ps[pr * BKV + (((0 + (lr >> 3)) ^ key) * 8) + (lr & 7)] = (bf16_t)p0;
        Ps[pr * BKV + (((2 + (lr >> 3)) ^ key) * 8) + (lr & 7)] = (bf16_t)p1;
        Ps[pr * BKV + (((4 + (lr >> 3)) ^ key) * 8) + (lr & 7)] = (bf16_t)p2;
        Ps[pr * BKV + (((6 + (lr >> 3)) ^ key) * 8) + (lr & 7)] = (bf16_t)p3;
        l_st[mi][r] += (p0 + p1) + (p2 + p3);
      }
    }
    // Ps wave-private -> no barrier

    // O += P V   (per wave: [32 q][128 d])
#pragma unroll
    for (int ki = 0; ki < 2; ++ki) {
      bf16x8 pf[2];
#pragma unroll
      for (int mi = 0; mi < 2; ++mi)
        pf[mi] = *(const bf16x8*)&Ps[(wv * 32 + mi * 16 + lr) * BKV + (((ki * 4 + quad) ^ (lr & 7)) * 8)];
#pragma unroll
      for (int di = 0; di < 8; ++di) {
        bf16x8 vf = *(const bf16x8*)&Vc[(di * 16 + lr) * BKV + (((ki * 4 + quad) ^ (lr & 7)) * 8)];
        __builtin_amdgcn_s_setprio(1);
#pragma unroll
        for (int mi = 0; mi < 2; ++mi)
          oacc[mi][di] = __builtin_amdgcn_mfma_f32_16x16x32_bf16(pf[mi], vf, oacc[mi][di], 0, 0, 0);
        __builtin_amdgcn_s_setprio(0);
      }
    }
  }

  // epilogue: reduce l across the 16 lr-lanes, O /= l, write ctx bf16
  bf16_t* Ob = O + (size_t)(b * SEQ + q0) * HIDDEN + h * HDIM;
#pragma unroll
  for (int mi = 0; mi < 2; ++mi) {
#pragma unroll
    for (int r = 0; r < 4; ++r) {
      float s = l_st[mi][r];
      s += __shfl_xor(s, 1);
      s += __shfl_xor(s, 2);
      s += __shfl_xor(s, 4);
      s += __shfl_xor(s, 8);
      float inv = 1.0f / s;
      size_t rowoff = (size_t)(wv * 32 + mi * 16 + quad * 4 + r) * HIDDEN;
#pragma unroll
      for (int di = 0; di < 8; ++di)
        Ob[rowoff + di * 16 + lr] = (bf16_t)(oacc[mi][di][r] * inv);
    }
  }
}

extern "C" void kernel_launch(void* const* d_in, const int* in_sizes, int n_in,
                              void* d_out, int out_size, void* d_ws, size_t ws_size,
                              hipStream_t stream) {
  const float* x   = (const float*)d_in[0];
  const float* msk = (const float*)d_in[1];
  const float* Wq  = (const float*)d_in[2];
  const float* bq  = (const float*)d_in[3];
  const float* Wk  = (const float*)d_in[4];
  const float* bk  = (const float*)d_in[5];
  const float* Wv  = (const float*)d_in[6];
  const float* bv  = (const float*)d_in[7];
  const float* Wo  = (const float*)d_in[8];
  const float* bo  = (const float*)d_in[9];
  float* out = (float*)d_out;

  // workspace layout (bf16 elems), ~101 MB total
  bf16_t* Xb   = (bf16_t*)d_ws;
  bf16_t* Wqkb = Xb   + (size_t)MTOT * HIDDEN;            // Wq|Wk stacked [4096][2048]
  bf16_t* Wvb  = Wqkb + (size_t)2 * HIDDEN * HIDDEN;
  bf16_t* Wob  = Wvb  + (size_t)HIDDEN * HIDDEN;
  bf16_t* QKo  = Wob  + (size_t)HIDDEN * HIDDEN;          // [4096][4096]
  bf16_t* Vto  = QKo  + (size_t)MTOT * 2 * HIDDEN;        // [2048][4096]
  float*  bqk  = (float*)(Vto + (size_t)HIDDEN * MTOT);   // [4096] fp32
  bf16_t* Cb   = Xb;  // ctx aliases Xb (Xb dead after Vt GEMM)

  // fused casts: 6 regions x (HH/4 float4 / 256) blocks
  cvt_all<<<dim3(HIDDEN * HIDDEN / 4 / 256, 6), 256, 0, stream>>>(
      x, Wq, Wk, Wv, Wo, Xb, Wqkb, Wvb, Wob);
  pack_bias2<<<2 * HIDDEN / 256, 256, 0, stream>>>(bq, bk, bqk);

  // QK projection: [4096,2048] x [4096,2048]^T -> [4096][4096]
  // gemm32: 256x128 tiles -> 16x32 = 512 WGs = exactly 2 blocks/CU
  gemm32<true, false><<<512, 512, 0, stream>>>(Xb, Wqkb, bqk, QKo, HIDDEN, 4096, 32);
  // V^T projection (swapped operands): [2048]x[4096], 256x128 tiles -> 256 WGs
  gemm_tall<true, true><<<256, 512, 0, stream>>>(Wvb, Xb, bv, Vto, HIDDEN, 4096, 32);
  // attention -> ctx bf16 [4096][2048]  (512-thread blocks, BQ=256, grid 256)
  attn_kernel<<<dim3(SEQ / BQ, BATCH * NHEADS), 512, 0, stream>>>(QKo, Vto, msk, Cb);
  // output projection -> fp32 out: [4096]x[2048], 256x128 tiles -> 256 WGs
  gemm_tall<false, false><<<256, 512, 0, stream>>>(Cb, Wob, bo, out, HIDDEN, 2048, 16);
}

// Round 10
// 389.998 us; speedup vs baseline: 1.0526x; 1.0526x over previous
//
#include <hip/hip_runtime.h>

typedef __bf16 bf16_t;
typedef bf16_t bf16x8 __attribute__((ext_vector_type(8)));
typedef float f32x4 __attribute__((ext_vector_type(4)));

#define HIDDEN 2048
#define SEQ 2048
#define BATCH 2
#define NHEADS 16
#define HDIM 128
#define MTOT (BATCH*SEQ)
#define SCALE 0.088388347648318447f
#define C1EXP2 0.12753102158508967f   /* SCALE * log2(e) */
#define LOG2E  1.4426950408889634f

// device exp2 without touching libm names (math.h macro collision on this toolchain)
__device__ __forceinline__ float dev_exp2(float x) { return __builtin_amdgcn_exp2f(x); }

// ---- async global->LDS (wave-uniform LDS base + lane*16, per m97) ----
typedef __attribute__((address_space(1))) const void gvoid_t;
typedef __attribute__((address_space(3))) void svoid_t;
__device__ __forceinline__ void async_copy16(const bf16_t* g, bf16_t* l) {
  __builtin_amdgcn_global_load_lds((gvoid_t*)g, (svoid_t*)l, 16, 0, 0);
}

// ---- fused fp32 -> bf16 cast for x + 4 weights (one dispatch) ----
__global__ void cvt_all(const float* __restrict__ x,  const float* __restrict__ wq,
                        const float* __restrict__ wk, const float* __restrict__ wv,
                        const float* __restrict__ wo,
                        bf16_t* __restrict__ xb, bf16_t* __restrict__ wqkb,
                        bf16_t* __restrict__ wvb, bf16_t* __restrict__ wob) {
  const size_t HH = (size_t)HIDDEN * HIDDEN;
  const float* src; bf16_t* dst;
  switch (blockIdx.y) {
    case 0:  src = x;        dst = xb;        break;
    case 1:  src = x + HH;   dst = xb + HH;   break;
    case 2:  src = wq;       dst = wqkb;      break;
    case 3:  src = wk;       dst = wqkb + HH; break;
    case 4:  src = wv;       dst = wvb;       break;
    default: src = wo;       dst = wob;       break;
  }
  int i = blockIdx.x * 256 + threadIdx.x;     // HH/4 float4s per region
  float4 v = reinterpret_cast<const float4*>(src)[i];
  union { bf16_t h[4]; uint2 u; } t;
  t.h[0] = (bf16_t)v.x; t.h[1] = (bf16_t)v.y; t.h[2] = (bf16_t)v.z; t.h[3] = (bf16_t)v.w;
  reinterpret_cast<uint2*>(dst)[i] = t.u;
}

__global__ void pack_bias2(const float* __restrict__ a, const float* __restrict__ b2,
                           float* __restrict__ out) {
  int i = blockIdx.x * 256 + threadIdx.x;      // 0..4095
  out[i] = (i < HIDDEN) ? a[i] : b2[i - HIDDEN];
}

// ---- 8-phase 256x256 GEMM (QK projection), relaxed split checkpoints ----
// R6 structure unchanged except CP placement/counts. Per-unit issue->wait
// cover (phases): A0 4, B0 5, A1 4, B1 3 (was: A1/B1 only 2 -> sub-HBM-
// latency stall each K-tile). CPs sit AFTER the MFMA cluster, before the
// closing barrier. Steady-state FIFO: after P3-CP queue = 8 loads
// [A1(t+1),B1(t+1),B0(t+2),A0(t+2)]; after P0-CP = 6. Tails drain via
// the t+2<nt guards (vmcnt(0) in the last two tiles only).
#define QKK 2048
#define RD_A(dst, buf, mh) do {                                                \
  _Pragma("unroll") for (int mi_ = 0; mi_ < 4; ++mi_)                          \
    _Pragma("unroll") for (int kk_ = 0; kk_ < 2; ++kk_)                        \
      dst[mi_][kk_] = *(const bf16x8*)&As[buf][mh][(wr * 64 + mi_ * 16 + lr) * 64 \
                         + (((kk_ * 4 + quad) ^ (lr & 7)) * 8)];               \
} while (0)
#define RD_B(dst, buf, nh) do {                                                \
  _Pragma("unroll") for (int ni_ = 0; ni_ < 2; ++ni_)                          \
    _Pragma("unroll") for (int kk_ = 0; kk_ < 2; ++kk_)                        \
      dst[ni_][kk_] = *(const bf16x8*)&Bs[buf][nh][(wc * 32 + ni_ * 16 + lr) * 64 \
                         + (((kk_ * 4 + quad) ^ (lr & 7)) * 8)];               \
} while (0)
#define MMQ(mh, nh, afr, bfr) do {                                             \
  __builtin_amdgcn_s_setprio(1);                                               \
  _Pragma("unroll") for (int mi_ = 0; mi_ < 4; ++mi_)                          \
    _Pragma("unroll") for (int ni_ = 0; ni_ < 2; ++ni_) {                      \
      acc[(mh)*4 + mi_][(nh)*2 + ni_] = __builtin_amdgcn_mfma_f32_16x16x32_bf16( \
          afr[mi_][0], bfr[ni_][0], acc[(mh)*4 + mi_][(nh)*2 + ni_], 0, 0, 0); \
      acc[(mh)*4 + mi_][(nh)*2 + ni_] = __builtin_amdgcn_mfma_f32_16x16x32_bf16( \
          afr[mi_][1], bfr[ni_][1], acc[(mh)*4 + mi_][(nh)*2 + ni_], 0, 0, 0); \
    }                                                                          \
  __builtin_amdgcn_s_setprio(0);                                               \
} while (0)
#define STG(ptr, t64, ldsbase) do {                                            \
  async_copy16((ptr) + (t64), (ldsbase));                                      \
  async_copy16((ptr) + (size_t)8 * QKK + (t64), (ldsbase) + 8 * 64);           \
} while (0)
#define PHASE_SYNC do { __builtin_amdgcn_s_barrier();                          \
  asm volatile("s_waitcnt lgkmcnt(0)" ::: "memory");                           \
  __builtin_amdgcn_sched_barrier(0); } while (0)

__global__ __launch_bounds__(512)
void gemm8p(const bf16_t* __restrict__ A, const bf16_t* __restrict__ Bt,
            const float* __restrict__ bias, bf16_t* __restrict__ Y) {
  __shared__ __align__(16) bf16_t As[2][2][128 * 64];   // 64 KB
  __shared__ __align__(16) bf16_t Bs[2][2][128 * 64];   // 64 KB
  const int tid  = threadIdx.x;
  const int lane = tid & 63;
  const int wv   = tid >> 6;                 // 0..7
  const int wr   = wv >> 2, wc = wv & 3;     // 2M x 4N wave grid
  const int lr   = lane & 15, quad = lane >> 4;

  // bijective XCD swizzle: 256 WGs, 32 contiguous per XCD
  const int wg  = blockIdx.x;
  const int swz = (wg & 7) * 32 + (wg >> 3);
  const int m0  = (swz >> 4) * 256;
  const int n0  = (swz & 15) * 256;

  f32x4 acc[8][4] = {};

  const int sub = lane >> 3, chv = (lane & 7) ^ sub;
  const int rih = wv * 16 + sub;
  const bf16_t* pA0 = A  + (size_t)(m0 +       rih) * QKK + chv * 8;
  const bf16_t* pA1 = A  + (size_t)(m0 + 128 + rih) * QKK + chv * 8;
  const bf16_t* pB0 = Bt + (size_t)(n0 +       rih) * QKK + chv * 8;
  const bf16_t* pB1 = Bt + (size_t)(n0 + 128 + rih) * QKK + chv * 8;
  const int lwo = wv * 16 * 64;
  const int nt  = QKK >> 6;

  // prologue (FIFO): B0(0) A0(0) A1(0) B1(0) B0(1) A0(1); vmcnt(8) retires
  // exactly B0(0),A0(0) and leaves the steady-state queue of 8.
  STG(pB0, (size_t)0,  &Bs[0][0][lwo]);
  STG(pA0, (size_t)0,  &As[0][0][lwo]);
  STG(pA1, (size_t)0,  &As[0][1][lwo]);
  STG(pB1, (size_t)0,  &Bs[0][1][lwo]);
  STG(pB0, (size_t)64, &Bs[1][0][lwo]);
  STG(pA0, (size_t)64, &As[1][0][lwo]);
  asm volatile("s_waitcnt vmcnt(8)" ::: "memory");
  __builtin_amdgcn_s_barrier();

  bf16x8 afr[4][2], bf0[2][2], bf1[2][2];

  for (int t = 0; t < nt; ++t) {
    const int p = t & 1;
    const size_t tk = (size_t)t * 64;

    // P0: Q(0,0) -- read A0,B0(t); stage A1(t+1); CP retires A1,B1(t)
    RD_A(afr, p, 0); RD_B(bf0, p, 0);
    if (t + 1 < nt) STG(pA1, tk + 64, &As[p ^ 1][1][lwo]);
    PHASE_SYNC; MMQ(0, 0, afr, bf0);
    if (t + 2 < nt) { asm volatile("s_waitcnt vmcnt(6)" ::: "memory"); }
    else            { asm volatile("s_waitcnt vmcnt(0)" ::: "memory"); }
    __builtin_amdgcn_s_barrier();

    // P1: Q(0,1) -- read B1(t), af retained; stage B1(t+1)
    RD_B(bf1, p, 1);
    if (t + 1 < nt) STG(pB1, tk + 64, &Bs[p ^ 1][1][lwo]);
    PHASE_SYNC; MMQ(0, 1, afr, bf1); __builtin_amdgcn_s_barrier();

    // P2: Q(1,1) -- read A1(t) (af0 dead); stage B0(t+2)
    RD_A(afr, p, 1);
    if (t + 2 < nt) STG(pB0, tk + 128, &Bs[p][0][lwo]);
    PHASE_SYNC; MMQ(1, 1, afr, bf1); __builtin_amdgcn_s_barrier();

    // P3: Q(1,0) -- bf0 retained; stage A0(t+2); CP retires A0,B0(t+1)
    if (t + 2 < nt) STG(pA0, tk + 128, &As[p][0][lwo]);
    PHASE_SYNC; MMQ(1, 0, afr, bf0);
    if (t + 2 < nt) { asm volatile("s_waitcnt vmcnt(8)" ::: "memory"); }
    else            { asm volatile("s_waitcnt vmcnt(0)" ::: "memory"); }
    __builtin_amdgcn_s_barrier();
  }

  // epilogue: col bias + cast + store
  float bc[4];
#pragma unroll
  for (int fn = 0; fn < 4; ++fn)
    bc[fn] = bias[n0 + (fn >> 1) * 128 + wc * 32 + (fn & 1) * 16 + lr];
#pragma unroll
  for (int fm = 0; fm < 8; ++fm) {
    const int rowb = m0 + (fm >> 2) * 128 + wr * 64 + (fm & 3) * 16 + quad * 4;
#pragma unroll
    for (int r = 0; r < 4; ++r) {
      const size_t base = (size_t)(rowb + r) * 4096;
#pragma unroll
      for (int fn = 0; fn < 4; ++fn) {
        const int col = n0 + (fn >> 1) * 128 + wc * 32 + (fn & 1) * 16 + lr;
        Y[base + col] = (bf16_t)(acc[fm][fn][r] + bc[fn]);
      }
    }
  }
}

// ---- gemm_tall: 256x128, BK=64, 3-deep pipeline; CP moved after P1 MFMA ----
#define TSTG(ptr, t64, ldsbase) do {                                           \
  async_copy16((ptr) + (t64), (ldsbase));                                      \
  async_copy16((ptr) + (size_t)8 * K + (t64), (ldsbase) + 8 * 64);             \
} while (0)
#define TRD(kk) do {                                                           \
  _Pragma("unroll") for (int fi_ = 0; fi_ < 4; ++fi_)                          \
    af[fi_] = *(const bf16x8*)&As[buf][(wr * 64 + fi_ * 16 + lr) * 64          \
                  + ((((kk) * 4 + quad) ^ (lr & 7)) * 8)];                     \
  _Pragma("unroll") for (int fi_ = 0; fi_ < 4; ++fi_)                          \
    bf[fi_] = *(const bf16x8*)&Bs[buf][(wc * 64 + fi_ * 16 + lr) * 64          \
                  + ((((kk) * 4 + quad) ^ (lr & 7)) * 8)];                     \
} while (0)
#define TMM() do {                                                             \
  __builtin_amdgcn_s_setprio(1);                                               \
  _Pragma("unroll") for (int fm_ = 0; fm_ < 4; ++fm_)                          \
    _Pragma("unroll") for (int fn_ = 0; fn_ < 4; ++fn_)                        \
      acc[fm_][fn_] = __builtin_amdgcn_mfma_f32_16x16x32_bf16(                 \
          af[fm_], bf[fn_], acc[fm_][fn_], 0, 0, 0);                           \
  __builtin_amdgcn_s_setprio(0);                                               \
} while (0)

template<bool OUT_BF16, bool ROW_BIAS>
__global__ __launch_bounds__(512)
void gemm_tall(const bf16_t* __restrict__ A, const bf16_t* __restrict__ Bt,
               const float* __restrict__ bias, void* __restrict__ Yv,
               int K, int ldY, int nbt) {
  __shared__ __align__(16) bf16_t As[3][256 * 64];   // 96 KB
  __shared__ __align__(16) bf16_t Bs[3][128 * 64];   // 48 KB
  const int tid  = threadIdx.x;
  const int lane = tid & 63;
  const int wv   = tid >> 6;                 // 0..7
  const int wr   = wv >> 1, wc = wv & 1;     // 4M x 2N wave grid
  const int lr   = lane & 15, quad = lane >> 4;

  // bijective XCD swizzle (gridDim.x == 256 at both call sites)
  const int wg  = blockIdx.x;
  const int swz = (wg & 7) * 32 + (wg >> 3);
  const int m0  = (swz / nbt) * 256;
  const int n0  = (swz % nbt) * 128;

  f32x4 acc[4][4] = {};

  const int sub = lane >> 3, chv = (lane & 7) ^ sub;
  const int rih = wv * 16 + sub;
  const bf16_t* pA = A  + (size_t)(m0 + rih) * K + chv * 8;   // A0 unit; A1 = +128*K
  const bf16_t* pB = Bt + (size_t)(n0 + rih) * K + chv * 8;
  const size_t a1off = (size_t)128 * K;
  const int lwo = wv * 16 * 64;
  const int nt  = K >> 6;

  // prologue: t0 (6 calls) then t1 (6 calls); vmcnt(6) -> t0 landed
  TSTG(pA,         (size_t)0,  &As[0][lwo]);
  TSTG(pA + a1off, (size_t)0,  &As[0][128 * 64 + lwo]);
  TSTG(pB,         (size_t)0,  &Bs[0][lwo]);
  TSTG(pA,         (size_t)64, &As[1][lwo]);
  TSTG(pA + a1off, (size_t)64, &As[1][128 * 64 + lwo]);
  TSTG(pB,         (size_t)64, &Bs[1][lwo]);
  asm volatile("s_waitcnt vmcnt(6)" ::: "memory");
  __builtin_amdgcn_s_barrier();

  bf16x8 af[4], bf[4];
  for (int t = 0; t < nt; ++t) {
    const int buf = t % 3;

    // P0 (kk=0): reads + stage all 3 units of t+2 -> buf (t+2)%3
    TRD(0);
    if (t + 2 < nt) {
      const int b2 = (buf < 1) ? buf + 2 : buf - 1;   // (t+2)%3
      const size_t tk2 = (size_t)(t + 2) * 64;
      TSTG(pA,         tk2, &As[b2][lwo]);
      TSTG(pA + a1off, tk2, &As[b2][128 * 64 + lwo]);
      TSTG(pB,         tk2, &Bs[b2][lwo]);
    }
    PHASE_SYNC; TMM(); __builtin_amdgcn_s_barrier();

    // P1 (kk=1): reads; CP AFTER the MFMA (max cover: t+1 issued t-1 P0,
    // waited end-of-t P1 ~= 3.5 phases) -- then barrier into next tile
    TRD(1);
    PHASE_SYNC; TMM();
    if (t + 2 < nt) { asm volatile("s_waitcnt vmcnt(6)" ::: "memory"); }
    else            { asm volatile("s_waitcnt vmcnt(0)" ::: "memory"); }
    __builtin_amdgcn_s_barrier();
  }

  // epilogue
  float bc[4];
  if (!ROW_BIAS) {
#pragma unroll
    for (int fn = 0; fn < 4; ++fn) bc[fn] = bias[n0 + wc * 64 + fn * 16 + lr];
  }
#pragma unroll
  for (int fm = 0; fm < 4; ++fm) {
    const int rowb = m0 + wr * 64 + fm * 16 + quad * 4;
#pragma unroll
    for (int r = 0; r < 4; ++r) {
      const int row = rowb + r;
      const float brow = ROW_BIAS ? bias[row] : 0.0f;
      const size_t base = (size_t)row * ldY;
#pragma unroll
      for (int fn = 0; fn < 4; ++fn) {
        const int col = n0 + wc * 64 + fn * 16 + lr;
        float y = acc[fm][fn][r] + (ROW_BIAS ? brow : bc[fn]);
        if (OUT_BF16) ((bf16_t*)Yv)[base + col] = (bf16_t)y;
        else          ((float*)Yv)[base + col]  = y;
      }
    }
  }
}

// ---- Flash attention v7 (R2/R4 best-measured version, BQ=128) ----
#define BQ 128
#define BKV 64
#define LDQK 4096

__global__ __launch_bounds__(256, 2)
void attn_kernel(const bf16_t* __restrict__ QK, const bf16_t* __restrict__ Vt,
                 const float* __restrict__ mask, bf16_t* __restrict__ O) {
  __shared__ __align__(16) bf16_t Ks[2][BKV * 128];  // 2 x 16 KB, swizzle key row&15
  __shared__ __align__(16) bf16_t Vs[HDIM * BKV];    // 16 KB, swizzle key d&7
  __shared__ __align__(16) bf16_t Ps[BQ * BKV];      // 16 KB, swizzle key row&7
  __shared__ __align__(16) float  Msk[SEQ];          // 8 KB, pre-scaled by log2e

  const int tid  = threadIdx.x;
  const int lane = tid & 63;
  const int wv   = tid >> 6;                       // wave owns q rows [wv*32, wv*32+32)
  const int lr   = lane & 15, quad = lane >> 4;
  const int q0   = blockIdx.x * BQ;
  const int bh   = blockIdx.y;
  const int b    = bh >> 4, h = bh & 15;

  const bf16_t* Qg = QK + (size_t)(b * SEQ + q0) * LDQK + h * HDIM;
  const bf16_t* Kg = QK + (size_t)(b * SEQ) * LDQK + HIDDEN + h * HDIM;
  const bf16_t* Vg = Vt + (size_t)(h * HDIM) * MTOT + b * SEQ;
  const float*  mb = mask + b * SEQ;

  // Q fragments straight from global (one-time; L2/L3-served). 32 VGPRs.
  bf16x8 qf[2][4];
#pragma unroll
  for (int mi = 0; mi < 2; ++mi)
#pragma unroll
    for (int dk = 0; dk < 4; ++dk)
      qf[mi][dk] = *(const bf16x8*)(Qg + (size_t)(wv * 32 + mi * 16 + lr) * LDQK + dk * 32 + quad * 8);

  // mask -> LDS once, pre-scaled (keeps the main loop free of compiler VMEM)
  for (int i = tid; i < SEQ / 4; i += 256) {
    float4 mv = reinterpret_cast<const float4*>(mb)[i];
    Msk[i * 4 + 0] = mv.x * LOG2E;
    Msk[i * 4 + 1] = mv.y * LOG2E;
    Msk[i * 4 + 2] = mv.z * LOG2E;
    Msk[i * 4 + 3] = mv.w * LOG2E;
  }

  // staging: K tile 64x128 = 16 calls (4/wave); V tile 128x64 = 16 calls (4/wave)
  const int kcs = lane & 15;                       // K chunk (16B units)
  const int vcs = lane & 7;                        // V chunk
  const bf16_t* kgp[4]; const bf16_t* vgp[4];
  int lKo[4], lVo[4];
#pragma unroll
  for (int i = 0; i < 4; ++i) {
    int kr = wv * 16 + i * 4 + (lane >> 4);        // 0..63
    kgp[i] = Kg + (size_t)kr * LDQK + ((kcs ^ (kr & 15)) * 8);
    lKo[i] = (wv * 16 + i * 4) * 128;              // wave-uniform; HW adds lane*16B
    int vr = wv * 32 + i * 8 + (lane >> 3);        // 0..127
    vgp[i] = Vg + (size_t)vr * MTOT + ((vcs ^ (vr & 7)) * 8);
    lVo[i] = (wv * 32 + i * 8) * 64;
  }

  // drain Q/mask VMEM so in-loop vmcnt counts only staging ops
  asm volatile("s_waitcnt vmcnt(0)" ::: "memory");
#pragma unroll
  for (int i = 0; i < 4; ++i) async_copy16(kgp[i], &Ks[0][lKo[i]]);  // K(0) in flight
  asm volatile("s_waitcnt lgkmcnt(0)" ::: "memory");                 // Msk writes done
  __builtin_amdgcn_s_barrier();                                      // Msk visible

  float l_st[2][4] = {};
  f32x4 oacc[2][8] = {};

  for (int kt = 0; kt < SEQ; kt += BKV) {
    const int cur = (kt >> 6) & 1;
    const bf16_t* Kc = &Ks[cur][0];

    // all prior ds ops (incl. PV's Vs reads) retired before tiles are re-staged
    asm volatile("s_waitcnt lgkmcnt(0)" ::: "memory");
    __builtin_amdgcn_s_barrier();   // all waves done reading Vs/Ps/Ks[cur^1]
#pragma unroll
    for (int i = 0; i < 4; ++i) async_copy16(vgp[i] + kt, &Vs[lVo[i]]);
    if (kt + BKV < SEQ) {
#pragma unroll
      for (int i = 0; i < 4; ++i)
        async_copy16(kgp[i] + (size_t)(kt + BKV) * LDQK, &Ks[cur ^ 1][lKo[i]]);
      asm volatile("s_waitcnt vmcnt(8)" ::: "memory");  // K(kt) landed
    } else {
      asm volatile("s_waitcnt vmcnt(4)" ::: "memory");  // K(kt) landed
    }
    __builtin_amdgcn_s_barrier();   // K(kt) visible to all waves
    __builtin_amdgcn_sched_barrier(0);

    float mk[4];
#pragma unroll
    for (int ni = 0; ni < 4; ++ni) mk[ni] = Msk[kt + ni * 16 + lr];

    // S = Q K^T  (per wave: [32 q][64 k])
    f32x4 sacc[2][4] = {};
#pragma unroll
    for (int dk = 0; dk < 4; ++dk) {
      bf16x8 kf[4];
#pragma unroll
      for (int ni = 0; ni < 4; ++ni)
        kf[ni] = *(const bf16x8*)&Kc[(ni * 16 + lr) * 128 + (((dk * 4 + quad) ^ lr) * 8)];
#pragma unroll
      for (int mi = 0; mi < 2; ++mi)
#pragma unroll
        for (int ni = 0; ni < 4; ++ni)
          sacc[mi][ni] = __builtin_amdgcn_mfma_f32_16x16x32_bf16(qf[mi][dk], kf[ni], sacc[mi][ni], 0, 0, 0);
    }

    // unnormalized P = exp2(S*C1 + mask*log2e); C-layout row = quad*4+r, col = lr
#pragma unroll
    for (int mi = 0; mi < 2; ++mi) {
#pragma unroll
      for (int r = 0; r < 4; ++r) {
        float p0 = dev_exp2(fmaf(sacc[mi][0][r], C1EXP2, mk[0]));
        float p1 = dev_exp2(fmaf(sacc[mi][1][r], C1EXP2, mk[1]));
        float p2 = dev_exp2(fmaf(sacc[mi][2][r], C1EXP2, mk[2]));
        float p3 = dev_exp2(fmaf(sacc[mi][3][r], C1EXP2, mk[3]));
        int pr = wv * 32 + mi * 16 + quad * 4 + r;
        int key = pr & 7;
        Ps[pr * BKV + (((0 + (lr >> 3)) ^ key) * 8) + (lr & 7)] = (bf16_t)p0;
        Ps[pr * BKV + (((2 + (lr >> 3)) ^ key) * 8) + (lr & 7)] = (bf16_t)p1;
        Ps[pr * BKV + (((4 + (lr >> 3)) ^ key) * 8) + (lr & 7)] = (bf16_t)p2;
        Ps[pr * BKV + (((6 + (lr >> 3)) ^ key) * 8) + (lr & 7)] = (bf16_t)p3;
        l_st[mi][r] += (p0 + p1) + (p2 + p3);
      }
    }

    if (kt + BKV < SEQ) {
      asm volatile("s_waitcnt vmcnt(4)" ::: "memory");  // V(kt) landed, K(kt+1) in flight
    } else {
      asm volatile("s_waitcnt vmcnt(0)" ::: "memory");  // final drain
    }
    __builtin_amdgcn_s_barrier();   // V(kt) visible (Ps is wave-private)
    __builtin_amdgcn_sched_barrier(0);

    // O += P V   (per wave: [32 q][128 d])
#pragma unroll
    for (int ki = 0; ki < 2; ++ki) {
      bf16x8 pf[2];
#pragma unroll
      for (int mi = 0; mi < 2; ++mi)
        pf[mi] = *(const bf16x8*)&Ps[(wv * 32 + mi * 16 + lr) * BKV + (((ki * 4 + quad) ^ (lr & 7)) * 8)];
#pragma unroll
      for (int di = 0; di < 8; ++di) {
        bf16x8 vf = *(const bf16x8*)&Vs[(di * 16 + lr) * BKV + (((ki * 4 + quad) ^ (lr & 7)) * 8)];
#pragma unroll
        for (int mi = 0; mi < 2; ++mi)
          oacc[mi][di] = __builtin_amdgcn_mfma_f32_16x16x32_bf16(pf[mi], vf, oacc[mi][di], 0, 0, 0);
      }
    }
  }

  // epilogue: reduce l across the 16 lr-lanes, O /= l, write ctx bf16
  bf16_t* Ob = O + (size_t)(b * SEQ + q0) * HIDDEN + h * HDIM;
#pragma unroll
  for (int mi = 0; mi < 2; ++mi) {
#pragma unroll
    for (int r = 0; r < 4; ++r) {
      float s = l_st[mi][r];
      s += __shfl_xor(s, 1);
      s += __shfl_xor(s, 2);
      s += __shfl_xor(s, 4);
      s += __shfl_xor(s, 8);
      float inv = 1.0f / s;
      size_t rowoff = (size_t)(wv * 32 + mi * 16 + quad * 4 + r) * HIDDEN;
#pragma unroll
      for (int di = 0; di < 8; ++di)
        Ob[rowoff + di * 16 + lr] = (bf16_t)(oacc[mi][di][r] * inv);
    }
  }
}

extern "C" void kernel_launch(void* const* d_in, const int* in_sizes, int n_in,
                              void* d_out, int out_size, void* d_ws, size_t ws_size,
                              hipStream_t stream) {
  const float* x   = (const float*)d_in[0];
  const float* msk = (const float*)d_in[1];
  const float* Wq  = (const float*)d_in[2];
  const float* bq  = (const float*)d_in[3];
  const float* Wk  = (const float*)d_in[4];
  const float* bk  = (const float*)d_in[5];
  const float* Wv  = (const float*)d_in[6];
  const float* bv  = (const float*)d_in[7];
  const float* Wo  = (const float*)d_in[8];
  const float* bo  = (const float*)d_in[9];
  float* out = (float*)d_out;

  // workspace layout (bf16 elems), ~101 MB total
  bf16_t* Xb   = (bf16_t*)d_ws;
  bf16_t* Wqkb = Xb   + (size_t)MTOT * HIDDEN;            // Wq|Wk stacked [4096][2048]
  bf16_t* Wvb  = Wqkb + (size_t)2 * HIDDEN * HIDDEN;
  bf16_t* Wob  = Wvb  + (size_t)HIDDEN * HIDDEN;
  bf16_t* QKo  = Wob  + (size_t)HIDDEN * HIDDEN;          // [4096][4096]
  bf16_t* Vto  = QKo  + (size_t)MTOT * 2 * HIDDEN;        // [2048][4096]
  float*  bqk  = (float*)(Vto + (size_t)HIDDEN * MTOT);   // [4096] fp32
  bf16_t* Cb   = Xb;  // ctx aliases Xb (Xb dead after Vt GEMM)

  // fused casts: 6 regions x (HH/4 float4 / 256) blocks
  cvt_all<<<dim3(HIDDEN * HIDDEN / 4 / 256, 6), 256, 0, stream>>>(
      x, Wq, Wk, Wv, Wo, Xb, Wqkb, Wvb, Wob);
  pack_bias2<<<2 * HIDDEN / 256, 256, 0, stream>>>(bq, bk, bqk);

  // QK projection: [4096,2048] x [4096,2048]^T -> [4096][4096]  (8-phase, 256 WGs)
  gemm8p<<<256, 512, 0, stream>>>(Xb, Wqkb, bqk, QKo);
  // V^T projection (swapped operands): [2048]x[4096], 256x128 tiles -> 256 WGs
  gemm_tall<true, true><<<256, 512, 0, stream>>>(Wvb, Xb, bv, Vto, HIDDEN, 4096, 32);
  // attention -> ctx bf16 [4096][2048]  (256-thread blocks, BQ=128, grid 512)
  attn_kernel<<<dim3(SEQ / BQ, BATCH * NHEADS), 256, 0, stream>>>(QKo, Vto, msk, Cb);
  // output projection -> fp32 out: [4096]x[2048], 256x128 tiles -> 256 WGs
  gemm_tall<false, false><<<256, 512, 0, stream>>>(Cb, Wob, bo, out, HIDDEN, 2048, 16);
}